// Round 5
// baseline (211.188 us; speedup 1.0000x reference)
//
#include <hip/hip_runtime.h>
#include <hip/hip_bf16.h>
#include <math.h>

namespace {

constexpr int BSZ = 2, LEN = 2048, DIM = 2048, NST = 16, RNK = 128;
constexpr int NC = 64, CHUNK = LEN / NC;          // 64 chunks of 32
constexpr int KS = 3 * RNK;                       // split-K = 384
constexpr float LOG2E = 1.4426950408889634f;
constexpr float LN2 = 0.6931471805599453f;

using bf16x8 = __attribute__((ext_vector_type(8))) short;
using f32x4  = __attribute__((ext_vector_type(4))) float;

__device__ __forceinline__ float fast_exp2(float x) {
#if __has_builtin(__builtin_amdgcn_exp2f)
  return __builtin_amdgcn_exp2f(x);
#else
  return exp2f(x);
#endif
}

__device__ __forceinline__ unsigned short bf16_rne(float x) {
  __hip_bfloat16 h = __float2bfloat16(x);
  return *(unsigned short*)&h;
}
__device__ __forceinline__ float bf16_tof(unsigned short u) {
  __hip_bfloat16 h = *(__hip_bfloat16*)&u;
  return __bfloat162float(h);
}

// ---------- Kernel 0: split f32 -> bf16 hi/lo, padded K=384 layouts ----------
// Ad: [B*L=4096][384] = [hi | lo | hi];  Bd: [D=2048][384] = [hi | hi | lo]
__global__ __launch_bounds__(256)
void split_bf16(const float* __restrict__ delta, const float* __restrict__ W,
                unsigned short* __restrict__ Ad, unsigned short* __restrict__ Bd) {
  int t = blockIdx.x * 256 + threadIdx.x;
  const int NA = BSZ * LEN * RNK;                 // 524288
  if (t < NA) {
    int row = t >> 7, k = t & (RNK - 1);
    float x = delta[t];
    unsigned short hi = bf16_rne(x);
    unsigned short lo = bf16_rne(x - bf16_tof(hi));
    unsigned short* p = Ad + (size_t)row * KS;
    p[k] = hi; p[RNK + k] = lo; p[2 * RNK + k] = hi;
  } else {
    t -= NA;                                      // 262144 W elements
    int row = t >> 7, k = t & (RNK - 1);
    float x = W[t];
    unsigned short hi = bf16_rne(x);
    unsigned short lo = bf16_rne(x - bf16_tof(hi));
    unsigned short* p = Bd + (size_t)row * KS;
    p[k] = hi; p[RNK + k] = hi; p[2 * RNK + k] = lo;
  }
}

// ---------- shared device fn: dt tile [32 l][256 d] via MFMA -> LDS ----------
// block = 256 thr (4 waves); wave w covers d_local = w*64 + [0,64)
__device__ __forceinline__ void compute_dt_tile(
    const unsigned short* __restrict__ Ad, const unsigned short* __restrict__ Bd,
    const float* __restrict__ bias, int b, int l0, int dgrp,
    float (*dt_tile)[256]) {
  const int lane = threadIdx.x & 63, w = threadIdx.x >> 6;
  const int r = lane & 15, kg = lane >> 4;
  const unsigned short* arow = Ad + (size_t)(b * LEN + l0 + r) * KS + kg * 8;
  const unsigned short* brow = Bd + (size_t)(dgrp * 256 + w * 64 + r) * KS + kg * 8;

  f32x4 acc[2][4] = {};
#pragma unroll
  for (int ks = 0; ks < KS / 32; ++ks) {          // 12 k-steps of 32
    bf16x8 af[2], bfr[4];
    af[0] = *(const bf16x8*)(arow + ks * 32);
    af[1] = *(const bf16x8*)(arow + (size_t)16 * KS + ks * 32);
#pragma unroll
    for (int n = 0; n < 4; ++n)
      bfr[n] = *(const bf16x8*)(brow + (size_t)n * 16 * KS + ks * 32);
#pragma unroll
    for (int m = 0; m < 2; ++m)
#pragma unroll
      for (int n = 0; n < 4; ++n)
        acc[m][n] = __builtin_amdgcn_mfma_f32_16x16x32_bf16(af[m], bfr[n], acc[m][n], 0, 0, 0);
  }
#pragma unroll
  for (int n = 0; n < 4; ++n) {
    const int dl = w * 64 + n * 16 + r;
    const float bs = bias[dgrp * 256 + dl];
#pragma unroll
    for (int m = 0; m < 2; ++m) {
      const int row0 = m * 16 + kg * 4;
#pragma unroll
      for (int j = 0; j < 4; ++j) {
        float z = acc[m][n][j] + bs;
        float sp = fmaxf(z, 0.f) + LN2 * __log2f(1.0f + fast_exp2(-fabsf(z) * LOG2E));
        dt_tile[row0 + j][dl] = sp;
      }
    }
  }
}

// ---------- Kernel 1: fused dt + local scan -> S (local state), sdt ----------
__global__ __launch_bounds__(256)
void scan1_fused(const unsigned short* __restrict__ Ad, const unsigned short* __restrict__ Bd,
                 const float* __restrict__ bias, const float* __restrict__ x,
                 const float* __restrict__ Bin, const float* __restrict__ Alog,
                 float* __restrict__ Sout, float* __restrict__ sdtout) {
  __shared__ float dt_tile[CHUNK][256];           // 32 KiB
  __shared__ float4 Bl[CHUNK * NST / 4];          // 2 KiB
  const int tid = threadIdx.x;
  const int bz = blockIdx.x;
  const int dgrp = bz & 7;
  const int c = (bz >> 3) & (NC - 1);
  const int b = bz >> 9;
  const int d = dgrp * 256 + tid;
  const int l0 = c * CHUNK;

  if (tid < CHUNK * NST / 4)
    Bl[tid] = ((const float4*)(Bin + ((size_t)b * LEN + l0) * NST))[tid];

  compute_dt_tile(Ad, Bd, bias, b, l0, dgrp, dt_tile);

  float A2[NST];
  {
    const float4* ap = (const float4*)(Alog + (size_t)d * NST);
#pragma unroll
    for (int q = 0; q < 4; ++q) {
      float4 v = ap[q];
      A2[q * 4 + 0] = -expf(v.x) * LOG2E;
      A2[q * 4 + 1] = -expf(v.y) * LOG2E;
      A2[q * 4 + 2] = -expf(v.z) * LOG2E;
      A2[q * 4 + 3] = -expf(v.w) * LOG2E;
    }
  }
  __syncthreads();

  float h[NST];
#pragma unroll
  for (int n = 0; n < NST; ++n) h[n] = 0.f;
  float sdt = 0.f;
  const float* xp = x + ((size_t)b * LEN + l0) * DIM + d;

  float xc = xp[0];
#pragma unroll 4
  for (int i = 0; i < CHUNK; ++i) {
    float xn = 0.f;
    if (i + 1 < CHUNK) xn = xp[(size_t)(i + 1) * DIM];
    float dt = dt_tile[i][tid];
    float dtx = dt * xc;
    sdt += dt;
#pragma unroll
    for (int q = 0; q < 4; ++q) {
      float4 Bv = Bl[i * 4 + q];
      float e0 = fast_exp2(dt * A2[q * 4 + 0]);
      float e1 = fast_exp2(dt * A2[q * 4 + 1]);
      float e2 = fast_exp2(dt * A2[q * 4 + 2]);
      float e3 = fast_exp2(dt * A2[q * 4 + 3]);
      h[q * 4 + 0] = fmaf(e0, h[q * 4 + 0], dtx * Bv.x);
      h[q * 4 + 1] = fmaf(e1, h[q * 4 + 1], dtx * Bv.y);
      h[q * 4 + 2] = fmaf(e2, h[q * 4 + 2], dtx * Bv.z);
      h[q * 4 + 3] = fmaf(e3, h[q * 4 + 3], dtx * Bv.w);
    }
    xc = xn;
  }

  const size_t obase = ((size_t)(b * NC + c) * DIM + d) * NST;
#pragma unroll
  for (int q = 0; q < 4; ++q) {
    float4 sv = {h[q * 4 + 0], h[q * 4 + 1], h[q * 4 + 2], h[q * 4 + 3]};
    *(float4*)&Sout[obase + q * 4] = sv;
  }
  sdtout[(size_t)(b * NC + c) * DIM + d] = sdt;
}

// ---------- Kernel 2: sequential combine; h_init written in-place into S ----------
__global__ __launch_bounds__(256)
void chunk_combine(const float* __restrict__ sdt, float* __restrict__ S,
                   const float* __restrict__ Alog) {
  const int t = blockIdx.x * 256 + threadIdx.x;   // B*D*N = 65536 threads
  const int n = t & (NST - 1);
  const int d = (t >> 4) & (DIM - 1);
  const int b = t >> 15;
  const float a2 = -expf(Alog[(size_t)d * NST + n]) * LOG2E;
  float cur = 0.f;
#pragma unroll 8
  for (int c = 0; c < NC; ++c) {
    const size_t idx = ((size_t)(b * NC + c) * DIM + d) * NST + n;
    float s = S[idx];
    float sd = sdt[(size_t)(b * NC + c) * DIM + d];
    S[idx] = cur;                                  // h_init for chunk c
    cur = fmaf(fast_exp2(sd * a2), cur, s);
  }
}

// ---------- Kernel 3: fused dt + re-scan from h_init, emit y + x*D ----------
__global__ __launch_bounds__(256)
void scan2_fused(const unsigned short* __restrict__ Ad, const unsigned short* __restrict__ Bd,
                 const float* __restrict__ bias, const float* __restrict__ x,
                 const float* __restrict__ Bin, const float* __restrict__ Cin,
                 const float* __restrict__ Alog, const float* __restrict__ Dpar,
                 const float* __restrict__ Hin, float* __restrict__ out) {
  __shared__ float dt_tile[CHUNK][256];           // 32 KiB
  __shared__ float4 Bl[CHUNK * NST / 4];
  __shared__ float4 Cl[CHUNK * NST / 4];
  const int tid = threadIdx.x;
  const int bz = blockIdx.x;
  const int dgrp = bz & 7;
  const int c = (bz >> 3) & (NC - 1);
  const int b = bz >> 9;
  const int d = dgrp * 256 + tid;
  const int l0 = c * CHUNK;

  if (tid < CHUNK * NST / 4)
    Bl[tid] = ((const float4*)(Bin + ((size_t)b * LEN + l0) * NST))[tid];
  else if (tid < CHUNK * NST / 2)
    Cl[tid - CHUNK * NST / 4] = ((const float4*)(Cin + ((size_t)b * LEN + l0) * NST))[tid - CHUNK * NST / 4];

  compute_dt_tile(Ad, Bd, bias, b, l0, dgrp, dt_tile);

  float A2[NST];
  {
    const float4* ap = (const float4*)(Alog + (size_t)d * NST);
#pragma unroll
    for (int q = 0; q < 4; ++q) {
      float4 v = ap[q];
      A2[q * 4 + 0] = -expf(v.x) * LOG2E;
      A2[q * 4 + 1] = -expf(v.y) * LOG2E;
      A2[q * 4 + 2] = -expf(v.z) * LOG2E;
      A2[q * 4 + 3] = -expf(v.w) * LOG2E;
    }
  }

  const size_t obase = ((size_t)(b * NC + c) * DIM + d) * NST;
  float h[NST];
#pragma unroll
  for (int q = 0; q < 4; ++q) {
    float4 hv = *(const float4*)&Hin[obase + q * 4];
    h[q * 4 + 0] = hv.x; h[q * 4 + 1] = hv.y; h[q * 4 + 2] = hv.z; h[q * 4 + 3] = hv.w;
  }
  const float dpar = Dpar[d];
  __syncthreads();

  const float* xp = x + ((size_t)b * LEN + l0) * DIM + d;
  float* op       = out + ((size_t)b * LEN + l0) * DIM + d;

  float xc = xp[0];
#pragma unroll 4
  for (int i = 0; i < CHUNK; ++i) {
    float xn = 0.f;
    if (i + 1 < CHUNK) xn = xp[(size_t)(i + 1) * DIM];
    float dt = dt_tile[i][tid];
    float dtx = dt * xc;
    float y0 = 0.f, y1 = 0.f, y2 = 0.f, y3 = 0.f;
#pragma unroll
    for (int q = 0; q < 4; ++q) {
      float4 Bv = Bl[i * 4 + q];
      float4 Cv = Cl[i * 4 + q];
      float e0 = fast_exp2(dt * A2[q * 4 + 0]);
      float e1 = fast_exp2(dt * A2[q * 4 + 1]);
      float e2 = fast_exp2(dt * A2[q * 4 + 2]);
      float e3 = fast_exp2(dt * A2[q * 4 + 3]);
      float hh0 = fmaf(e0, h[q * 4 + 0], dtx * Bv.x);
      float hh1 = fmaf(e1, h[q * 4 + 1], dtx * Bv.y);
      float hh2 = fmaf(e2, h[q * 4 + 2], dtx * Bv.z);
      float hh3 = fmaf(e3, h[q * 4 + 3], dtx * Bv.w);
      h[q * 4 + 0] = hh0; h[q * 4 + 1] = hh1; h[q * 4 + 2] = hh2; h[q * 4 + 3] = hh3;
      float yq = hh0 * Cv.x;
      yq = fmaf(hh1, Cv.y, yq);
      yq = fmaf(hh2, Cv.z, yq);
      yq = fmaf(hh3, Cv.w, yq);
      if (q == 0) y0 = yq; else if (q == 1) y1 = yq; else if (q == 2) y2 = yq; else y3 = yq;
    }
    op[(size_t)i * DIM] = fmaf(xc, dpar, (y0 + y1) + (y2 + y3));
    xc = xn;
  }
}

}  // namespace

extern "C" void kernel_launch(void* const* d_in, const int* in_sizes, int n_in,
                              void* d_out, int out_size, void* d_ws, size_t ws_size,
                              hipStream_t stream) {
  const float* x     = (const float*)d_in[0];
  const float* delta = (const float*)d_in[1];
  const float* Bin   = (const float*)d_in[2];
  const float* Cin   = (const float*)d_in[3];
  const float* Wdt   = (const float*)d_in[4];
  const float* bdt   = (const float*)d_in[5];
  const float* Alog  = (const float*)d_in[6];
  const float* Dpar  = (const float*)d_in[7];
  float* out = (float*)d_out;

  char* ws = (char*)d_ws;
  size_t off = 0;
  float* S   = (float*)(ws + off); off += (size_t)BSZ * NC * DIM * NST * 4;     // 16 MiB
  float* sdt = (float*)(ws + off); off += (size_t)BSZ * NC * DIM * 4;           // 1 MiB
  unsigned short* Ad = (unsigned short*)(ws + off); off += (size_t)BSZ * LEN * KS * 2;  // 3 MiB
  unsigned short* Bd = (unsigned short*)(ws + off); off += (size_t)DIM * KS * 2;        // 1.5 MiB

  split_bf16<<<(BSZ * LEN * RNK + DIM * RNK) / 256, 256, 0, stream>>>(delta, Wdt, Ad, Bd);
  scan1_fused<<<BSZ * NC * (DIM / 256), 256, 0, stream>>>(Ad, Bd, bdt, x, Bin, Alog, S, sdt);
  chunk_combine<<<BSZ * DIM * NST / 256, 256, 0, stream>>>(sdt, S, Alog);
  scan2_fused<<<BSZ * NC * (DIM / 256), 256, 0, stream>>>(Ad, Bd, bdt, x, Bin, Cin, Alog, Dpar, S, out);
}